// Round 11
// baseline (104.825 us; speedup 1.0000x reference)
//
#include <hip/hip_runtime.h>
#include <math.h>

#define T_TOK 1024
#define H_DIM 1024
#define NEXP  16
#define I_DIM 512
#define ISH   1024
#define GU_GRID 640
#define DN_GRID 1024

typedef __bf16 bf16;
typedef __bf16 bf16x4 __attribute__((ext_vector_type(4)));
typedef __bf16 bf16x8 __attribute__((ext_vector_type(8)));
typedef float  f32x4  __attribute__((ext_vector_type(4)));
typedef unsigned int u32;

#define MFMA(a,b,c) __builtin_amdgcn_mfma_f32_16x16x32_bf16(a,b,c,0,0,0)

__device__ __forceinline__ bf16x8 cvt8(float4 a, float4 b) {
    return (bf16x8){ (bf16)a.x,(bf16)a.y,(bf16)a.z,(bf16)a.w,
                     (bf16)b.x,(bf16)b.y,(bf16)b.z,(bf16)b.w };
}
__device__ __forceinline__ void gload16(const void* g, void* l) {
    __builtin_amdgcn_global_load_lds((const __attribute__((address_space(1))) u32*)g,
                                     (__attribute__((address_space(3))) u32*)l, 16, 0, 0);
}
#define WAIT_LGKM0 asm volatile("s_waitcnt lgkmcnt(0)" ::: "memory")
#define WAIT_VM0   asm volatile("s_waitcnt vmcnt(0)" ::: "memory")
#define SBAR       __builtin_amdgcn_s_barrier()

// ---------------- fused cast(x->bf16) + router ----------------
__global__ __launch_bounds__(256) void k_cast_router(const float* __restrict__ x,
        const float* __restrict__ gw, const float* __restrict__ bias,
        bf16* __restrict__ xb, int* __restrict__ tok_e, float* __restrict__ tok_w)
{
    int t = blockIdx.x * 4 + (threadIdx.x >> 6);
    int lane = threadIdx.x & 63;
    const float* xrow = x + (size_t)t * H_DIM + lane * 16;
    bf16* xbrow = xb + (size_t)t * H_DIM + lane * 16;
    float acc[NEXP];
    #pragma unroll
    for (int e = 0; e < NEXP; ++e) acc[e] = 0.f;
    #pragma unroll
    for (int kc = 0; kc < 4; ++kc) {
        float4 xv = *(const float4*)(xrow + kc * 4);
        bf16x4 o = { (bf16)xv.x, (bf16)xv.y, (bf16)xv.z, (bf16)xv.w };
        *(bf16x4*)(xbrow + kc * 4) = o;
        const float* gp = gw + lane * 16 + kc * 4;
        #pragma unroll
        for (int e = 0; e < NEXP; ++e) {
            float4 wv = *(const float4*)(gp + e * H_DIM);
            acc[e] += xv.x * wv.x + xv.y * wv.y + xv.z * wv.z + xv.w * wv.w;
        }
    }
    #pragma unroll
    for (int e = 0; e < NEXP; ++e) {
        float v = acc[e];
        #pragma unroll
        for (int off = 1; off < 64; off <<= 1) v += __shfl_xor(v, off);
        acc[e] = v;
    }
    if (lane == 0) {
        float sc[NEXP], bi[NEXP];
        #pragma unroll
        for (int e = 0; e < NEXP; ++e) {
            sc[e] = 1.f / (1.f + expf(-acc[e]));
            bi[e] = sc[e] + bias[e];
        }
        int i1 = 0; float b1 = bi[0];
        for (int e = 1; e < NEXP; ++e) if (bi[e] > b1) { b1 = bi[e]; i1 = e; }
        int i2 = -1; float b2 = -1e30f;
        for (int e = 0; e < NEXP; ++e) { if (e == i1) continue; if (bi[e] > b2) { b2 = bi[e]; i2 = e; } }
        float w1 = sc[i1], w2 = sc[i2];
        float s = w1 + w2;
        w1 /= s; w2 /= s;
        tok_e[t * 2]     = i1;  tok_e[t * 2 + 1] = i2;
        tok_w[t * 2]     = w1;  tok_w[t * 2 + 1] = w2;
    }
}

// ---------------- build: histogram + scan + scatter + BM=64 worklists ----------------
// entry: (ge<<20)|(mt<<12)|nx ; ge==16 => shared
__global__ __launch_bounds__(256) void k_build(const int* __restrict__ tok_e,
        const float* __restrict__ tok_w, int* __restrict__ offs_g,
        int* __restrict__ row_token, float* __restrict__ row_w,
        int* __restrict__ wl_gu, int* __restrict__ n_gu,
        int* __restrict__ wl_dn, int* __restrict__ n_dn)
{
    __shared__ int cnt[NEXP], cur[NEXP], tcnt[NEXP], toff[NEXP + 1];
    int tid = threadIdx.x;
    if (tid < NEXP) cnt[tid] = 0;
    __syncthreads();
    for (int p = tid; p < 2 * T_TOK; p += 256) atomicAdd(&cnt[tok_e[p]], 1);
    __syncthreads();
    if (tid == 0) {
        int s = 0, ts = 0;
        for (int e = 0; e < NEXP; ++e) {
            offs_g[e] = s; cur[e] = s;
            tcnt[e] = (cnt[e] + 63) >> 6;
            toff[e] = ts; ts += tcnt[e]; s += cnt[e];
        }
        offs_g[NEXP] = s; toff[NEXP] = ts;
        *n_gu = ts * 8 + 256;     // routed: 8 nx ; shared: 16 mt * 16 nx
        *n_dn = ts * 16 + 256;    // routed: 16 nx ; shared: 16 mt * 16 nx
    }
    __syncthreads();
    for (int p = tid; p < 2 * T_TOK; p += 256) {
        int e = tok_e[p];
        int pos = atomicAdd(&cur[e], 1);
        row_token[pos] = p >> 1;
        row_w[pos] = tok_w[p];
    }
    int ntr = toff[NEXP];
    int tot_gu = ntr * 8 + 256;
    for (int idx = tid; idx < tot_gu; idx += 256) {
        int entry;
        if (idx < ntr * 8) {
            int t8 = idx >> 3;
            int e = 0;
            while (!(t8 >= toff[e] && t8 < toff[e + 1])) ++e;
            int j = idx - toff[e] * 8;
            int nx = j / tcnt[e], mt = j % tcnt[e];
            entry = (e << 20) | (mt << 12) | nx;
        } else {
            int j = idx - ntr * 8;
            int nx = j >> 4, mt = j & 15;
            entry = (16 << 20) | (mt << 12) | nx;
        }
        wl_gu[idx] = entry;
    }
    int tot_dn = ntr * 16 + 256;
    for (int idx = tid; idx < tot_dn; idx += 256) {
        int entry;
        if (idx < ntr * 16) {
            int t16 = idx >> 4;
            int e = 0;
            while (!(t16 >= toff[e] && t16 < toff[e + 1])) ++e;
            int j = idx - toff[e] * 16;
            int nx = j / tcnt[e], mt = j % tcnt[e];
            entry = (e << 20) | (mt << 12) | nx;
        } else {
            int j = idx - ntr * 16;
            int nx = j >> 4, mt = j & 15;
            entry = (16 << 20) | (mt << 12) | nx;
        }
        wl_dn[idx] = entry;
    }
}

// ---------------- gate_up + SwiGLU: BM=64, BN=64g+64u, BK=64, dbuf pipeline ----------------
// A: global_load_lds (swizzled source, linear LDS); B: reg-stage fp32 -> cvt -> bf16 LDS (pad 72)
__global__ __launch_bounds__(256) void k_gu(
    const bf16* __restrict__ xb, const float* __restrict__ wgu, const float* __restrict__ sgu,
    bf16* __restrict__ act, bf16* __restrict__ act2,
    const int* __restrict__ offs, const int* __restrict__ row_token,
    const int* __restrict__ wl, const int* __restrict__ n_wl)
{
    __shared__ char A_l[2 * 8192];          // [64][64] bf16, XOR-swizzled
    __shared__ bf16 Gl[2][64][72];
    __shared__ bf16 Ul[2][64][72];
    __shared__ int  toks[64];

    int bid = blockIdx.x;
    int idx = (bid & 7) * (GU_GRID >> 3) + (bid >> 3);
    if (idx >= *n_wl) return;
    int entry = wl[idx];
    int ge = entry >> 20;
    bool sh = (ge == 16);
    int mt = (entry >> 12) & 255, nx = entry & 255;
    int n0 = nx * 64;
    int m0, mcnt, ldo;
    const float *Wg, *Wu;
    bf16* dst;
    if (sh) {
        m0 = mt * 64; mcnt = 64; ldo = ISH; dst = act2;
        Wg = sgu + (size_t)n0 * H_DIM;
        Wu = sgu + (size_t)(ISH + n0) * H_DIM;
    } else {
        m0 = offs[ge] + mt * 64; mcnt = min(64, offs[ge + 1] - m0);
        ldo = I_DIM; dst = act;
        const float* W = wgu + (size_t)ge * (2 * (size_t)I_DIM * H_DIM);
        Wg = W + (size_t)n0 * H_DIM;
        Wu = W + (size_t)(I_DIM + n0) * H_DIM;
    }

    int tid = threadIdx.x;
    if (tid < 64) toks[tid] = sh ? (m0 + tid) : row_token[m0 + min(tid, mcnt - 1)];
    __syncthreads();

    // A staging sources (2 x 16B per thread), inverse-swizzled on source side
    const bf16* srcA[2]; int offA[2];
    #pragma unroll
    for (int c = 0; c < 2; ++c) {
        int o = (c * 256 + tid) * 16;
        int r = o >> 7;
        int cb = (o & 127) ^ ((r & 7) << 4);
        srcA[c] = xb + (size_t)toks[r] * H_DIM + (cb >> 1);
        offA[c] = o;
    }
    // B staging: thread owns row rg, 16 fp32 at col cg
    int rg = tid >> 2, cg = (tid & 3) * 16;
    const float* pG = Wg + (size_t)rg * H_DIM + cg;
    const float* pU = Wu + (size_t)rg * H_DIM + cg;

    int lane = tid & 63, w = tid >> 6, wm = w >> 1, wn = w & 1;
    int lr = lane & 15, hi = lane >> 4, lk8 = hi * 8;

    f32x4 aG[2][2], aU[2][2];
    #pragma unroll
    for (int m = 0; m < 2; ++m)
        #pragma unroll
        for (int n = 0; n < 2; ++n) { aG[m][n] = (f32x4){0,0,0,0}; aU[m][n] = (f32x4){0,0,0,0}; }

    // ---- prologue: tile 0 ----
    {
        float4 g0 = *(const float4*)(pG),     g1 = *(const float4*)(pG + 4);
        float4 g2 = *(const float4*)(pG + 8), g3 = *(const float4*)(pG + 12);
        float4 u0 = *(const float4*)(pU),     u1 = *(const float4*)(pU + 4);
        float4 u2 = *(const float4*)(pU + 8), u3 = *(const float4*)(pU + 12);
        gload16(srcA[0], A_l + offA[0]);
        gload16(srcA[1], A_l + offA[1]);
        *(bf16x8*)&Gl[0][rg][cg]     = cvt8(g0, g1);
        *(bf16x8*)&Gl[0][rg][cg + 8] = cvt8(g2, g3);
        *(bf16x8*)&Ul[0][rg][cg]     = cvt8(u0, u1);
        *(bf16x8*)&Ul[0][rg][cg + 8] = cvt8(u2, u3);
        WAIT_LGKM0; WAIT_VM0; SBAR;
    }

    for (int t = 0; t < 16; ++t) {
        int c = t & 1;
        bool pf = (t + 1 < 16);
        float4 g0, g1, g2, g3, u0, u1, u2, u3;
        if (pf) {
            int kb = (t + 1) * 64;
            g0 = *(const float4*)(pG + kb);      g1 = *(const float4*)(pG + kb + 4);
            g2 = *(const float4*)(pG + kb + 8);  g3 = *(const float4*)(pG + kb + 12);
            u0 = *(const float4*)(pU + kb);      u1 = *(const float4*)(pU + kb + 4);
            u2 = *(const float4*)(pU + kb + 8);  u3 = *(const float4*)(pU + kb + 12);
            gload16(srcA[0] + kb, A_l + (c ^ 1) * 8192 + offA[0]);
            gload16(srcA[1] + kb, A_l + (c ^ 1) * 8192 + offA[1]);
        }
        const char* Ab = A_l + c * 8192;
        #pragma unroll
        for (int ks = 0; ks < 2; ++ks) {
            bf16x8 fa[2], fg[2], fu[2];
            #pragma unroll
            for (int mf = 0; mf < 2; ++mf) {
                int r = wm * 32 + mf * 16 + lr;
                fa[mf] = *(const bf16x8*)(Ab + r * 128 + (((ks * 32 + lk8) * 2) ^ ((r & 7) << 4)));
            }
            #pragma unroll
            for (int nf = 0; nf < 2; ++nf) {
                int r = wn * 32 + nf * 16 + lr;
                fg[nf] = *(const bf16x8*)&Gl[c][r][ks * 32 + lk8];
                fu[nf] = *(const bf16x8*)&Ul[c][r][ks * 32 + lk8];
            }
            #pragma unroll
            for (int mf = 0; mf < 2; ++mf)
                #pragma unroll
                for (int nf = 0; nf < 2; ++nf) {
                    aG[mf][nf] = MFMA(fa[mf], fg[nf], aG[mf][nf]);
                    aU[mf][nf] = MFMA(fa[mf], fu[nf], aU[mf][nf]);
                }
        }
        if (pf) {
            *(bf16x8*)&Gl[c ^ 1][rg][cg]     = cvt8(g0, g1);
            *(bf16x8*)&Gl[c ^ 1][rg][cg + 8] = cvt8(g2, g3);
            *(bf16x8*)&Ul[c ^ 1][rg][cg]     = cvt8(u0, u1);
            *(bf16x8*)&Ul[c ^ 1][rg][cg + 8] = cvt8(u2, u3);
            WAIT_LGKM0; WAIT_VM0; SBAR;
        }
    }

    #pragma unroll
    for (int mf = 0; mf < 2; ++mf) {
        #pragma unroll
        for (int j = 0; j < 4; ++j) {
            int rl = wm * 32 + mf * 16 + hi * 4 + j;
            if (rl < mcnt) {
                #pragma unroll
                for (int nf = 0; nf < 2; ++nf) {
                    float g = aG[mf][nf][j], u = aU[mf][nf][j];
                    float v = (g / (1.f + __expf(-g))) * u;
                    dst[(size_t)(m0 + rl) * ldo + n0 + wn * 32 + nf * 16 + lr] = (bf16)v;
                }
            }
        }
    }
}

// ---------------- down proj: BM=64, BN=64, BK=64, dbuf pipeline, atomic out ----------------
__global__ __launch_bounds__(256) void k_dn(
    const bf16* __restrict__ act, const bf16* __restrict__ act2,
    const float* __restrict__ wd, const float* __restrict__ sd, float* __restrict__ out,
    const int* __restrict__ offs, const int* __restrict__ row_token, const float* __restrict__ row_w,
    const int* __restrict__ wl, const int* __restrict__ n_wl)
{
    __shared__ char A_l[2 * 8192];
    __shared__ bf16 Bl[2][64][72];

    int bid = blockIdx.x;
    int idx = (bid & 7) * (DN_GRID >> 3) + (bid >> 3);
    if (idx >= *n_wl) return;
    int entry = wl[idx];
    int ge = entry >> 20;
    bool sh = (ge == 16);
    int mt = (entry >> 12) & 255, nx = entry & 255;
    int n0 = nx * 64;
    int m0, mcnt, lda, ldw, nt;
    const bf16* A;
    const float* W;
    if (sh) {
        m0 = mt * 64; mcnt = 64; A = act2; lda = ISH; W = sd + (size_t)n0 * ISH; ldw = ISH; nt = 16;
    } else {
        m0 = offs[ge] + mt * 64; mcnt = min(64, offs[ge + 1] - m0);
        A = act; lda = I_DIM; W = wd + (size_t)ge * H_DIM * I_DIM + (size_t)n0 * I_DIM; ldw = I_DIM; nt = 8;
    }

    int tid = threadIdx.x;
    const bf16* srcA[2]; int offA[2];
    #pragma unroll
    for (int c = 0; c < 2; ++c) {
        int o = (c * 256 + tid) * 16;
        int r = o >> 7;
        int cb = (o & 127) ^ ((r & 7) << 4);
        srcA[c] = A + (size_t)(m0 + min(r, mcnt - 1)) * lda + (cb >> 1);
        offA[c] = o;
    }
    int rg = tid >> 2, cg = (tid & 3) * 16;
    const float* pB = W + (size_t)rg * ldw + cg;

    int lane = tid & 63, w = tid >> 6, wm = w >> 1, wn = w & 1;
    int lr = lane & 15, hi = lane >> 4, lk8 = hi * 8;

    f32x4 acc[2][2];
    #pragma unroll
    for (int m = 0; m < 2; ++m)
        #pragma unroll
        for (int n = 0; n < 2; ++n) acc[m][n] = (f32x4){0,0,0,0};

    {
        float4 b0 = *(const float4*)(pB),     b1 = *(const float4*)(pB + 4);
        float4 b2 = *(const float4*)(pB + 8), b3 = *(const float4*)(pB + 12);
        gload16(srcA[0], A_l + offA[0]);
        gload16(srcA[1], A_l + offA[1]);
        *(bf16x8*)&Bl[0][rg][cg]     = cvt8(b0, b1);
        *(bf16x8*)&Bl[0][rg][cg + 8] = cvt8(b2, b3);
        WAIT_LGKM0; WAIT_VM0; SBAR;
    }

    for (int t = 0; t < nt; ++t) {
        int c = t & 1;
        bool pf = (t + 1 < nt);
        float4 b0, b1, b2, b3;
        if (pf) {
            int kb = (t + 1) * 64;
            b0 = *(const float4*)(pB + kb);      b1 = *(const float4*)(pB + kb + 4);
            b2 = *(const float4*)(pB + kb + 8);  b3 = *(const float4*)(pB + kb + 12);
            gload16(srcA[0] + kb, A_l + (c ^ 1) * 8192 + offA[0]);
            gload16(srcA[1] + kb, A_l + (c ^ 1) * 8192 + offA[1]);
        }
        const char* Ab = A_l + c * 8192;
        #pragma unroll
        for (int ks = 0; ks < 2; ++ks) {
            bf16x8 fa[2], fb[2];
            #pragma unroll
            for (int mf = 0; mf < 2; ++mf) {
                int r = wm * 32 + mf * 16 + lr;
                fa[mf] = *(const bf16x8*)(Ab + r * 128 + (((ks * 32 + lk8) * 2) ^ ((r & 7) << 4)));
            }
            #pragma unroll
            for (int nf = 0; nf < 2; ++nf) {
                int r = wn * 32 + nf * 16 + lr;
                fb[nf] = *(const bf16x8*)&Bl[c][r][ks * 32 + lk8];
            }
            #pragma unroll
            for (int mf = 0; mf < 2; ++mf)
                #pragma unroll
                for (int nf = 0; nf < 2; ++nf)
                    acc[mf][nf] = MFMA(fa[mf], fb[nf], acc[mf][nf]);
        }
        if (pf) {
            *(bf16x8*)&Bl[c ^ 1][rg][cg]     = cvt8(b0, b1);
            *(bf16x8*)&Bl[c ^ 1][rg][cg + 8] = cvt8(b2, b3);
            WAIT_LGKM0; WAIT_VM0; SBAR;
        }
    }

    #pragma unroll
    for (int mf = 0; mf < 2; ++mf) {
        #pragma unroll
        for (int j = 0; j < 4; ++j) {
            int rl = wm * 32 + mf * 16 + hi * 4 + j;
            if (rl < mcnt) {
                if (sh) {
                    #pragma unroll
                    for (int nf = 0; nf < 2; ++nf)
                        atomicAdd(&out[(size_t)(m0 + rl) * H_DIM + n0 + wn * 32 + nf * 16 + lr],
                                  acc[mf][nf][j]);
                } else {
                    int tk = row_token[m0 + rl];
                    float wt = row_w[m0 + rl];
                    #pragma unroll
                    for (int nf = 0; nf < 2; ++nf)
                        atomicAdd(&out[(size_t)tk * H_DIM + n0 + wn * 32 + nf * 16 + lr],
                                  wt * acc[mf][nf][j]);
                }
            }
        }
    }
}

extern "C" void kernel_launch(void* const* d_in, const int* in_sizes, int n_in,
                              void* d_out, int out_size, void* d_ws, size_t ws_size,
                              hipStream_t stream)
{
    (void)in_sizes; (void)n_in; (void)out_size; (void)ws_size;
    const float* x    = (const float*)d_in[0];
    const float* gw   = (const float*)d_in[1];
    const float* bias = (const float*)d_in[2];
    const float* wgu  = (const float*)d_in[3];
    const float* wd   = (const float*)d_in[4];
    const float* sgu  = (const float*)d_in[5];
    const float* sd   = (const float*)d_in[6];
    float* out = (float*)d_out;

    char* ws = (char*)d_ws;
    int*   offs_g    = (int*)(ws);
    int*   n_gu      = (int*)(ws + 128);
    int*   n_dn      = (int*)(ws + 132);
    int*   wl_gu     = (int*)(ws + 1024);
    int*   wl_dn     = (int*)(ws + 16384);
    int*   tok_e     = (int*)(ws + 32768);
    float* tok_w     = (float*)(ws + 40960);
    int*   row_token = (int*)(ws + 49152);
    float* row_w     = (float*)(ws + 57344);
    bf16*  xb        = (bf16*)(ws + 65536);
    bf16*  act       = (bf16*)(ws + 65536 + (1 << 21));
    bf16*  act2      = (bf16*)(ws + 65536 + (2 << 21));

    hipMemsetAsync(out, 0, (size_t)T_TOK * H_DIM * sizeof(float), stream);
    k_cast_router<<<T_TOK / 4, 256, 0, stream>>>(x, gw, bias, xb, tok_e, tok_w);
    k_build<<<1, 256, 0, stream>>>(tok_e, tok_w, offs_g, row_token, row_w,
                                   wl_gu, n_gu, wl_dn, n_dn);
    k_gu<<<GU_GRID, 256, 0, stream>>>(xb, wgu, sgu, act, act2,
                                      offs_g, row_token, wl_gu, n_gu);
    k_dn<<<DN_GRID, 256, 0, stream>>>(act, act2, wd, sd, out,
                                      offs_g, row_token, row_w, wl_dn, n_dn);
}